// Round 14
// baseline (2682.645 us; speedup 1.0000x reference)
//
#include <hip/hip_runtime.h>
#include <hip/hip_bf16.h>

using bf16 = __hip_bfloat16;
typedef __attribute__((ext_vector_type(8))) short bf16x8;   // 8 bf16 (4 VGPRs)
typedef __attribute__((ext_vector_type(4))) float f32x4;
typedef __attribute__((ext_vector_type(4))) int i32x4;

#define T_DIM 8192
#define DM    4096
#define DFF   14336

#define MFMA(va, vb, vc) __builtin_amdgcn_mfma_f32_16x16x32_bf16(va, vb, vc, 0, 0, 0)

// ---------------------------------------------------------------- helpers
__device__ __forceinline__ void gld_lds16(const bf16* gsrc, bf16* ldst) {
  auto* g = (const __attribute__((address_space(1))) unsigned int*)gsrc;
  auto* l = (__attribute__((address_space(3))) unsigned int*)ldst;
  __builtin_amdgcn_global_load_lds(g, l, 16, 0, 0);
}

// Prologue-only staging helper (full address math; one-time cost).
__device__ __forceinline__ void stage8k(const bf16* __restrict__ gbase, long lda,
                                        long grow0, long k0, bf16* lds_tile,
                                        int gran0, int tid) {
  const int g = gran0 + tid;            // granule index within tile
  const int row = g >> 3, c16 = g & 7;  // 8 granules (128B) per row
  const bf16* src = gbase + (grow0 + row) * lda + k0 + ((long)(c16 ^ (row & 7)) << 3);
  bf16* dst = lds_tile + ((size_t)(gran0 + (tid & ~63)) << 3);  // wave-uniform base
  gld_lds16(src, dst);
}

// LDS frag reads: per-thread loop-invariant base + compile-time imm offset.
#define LDA8(PB, H, M, KK) (*(const bf16x8*)(aP##KK + (PB) + (H) * 16384 + (M) * 4096))
#define LDB8(PB, N, KK)    (*(const bf16x8*)(bP##KK + (PB) + (N) * 8192))

// Phase boundary: NO manual lgkm drain — reads are compiler-visible, hipcc
// inserts minimal counted lgkm waits for actual MFMA deps. sched_barrier
// pins regions; setprio favors the MFMA cluster.
#define PH_B()                               \
  __builtin_amdgcn_sched_barrier(0);         \
  __builtin_amdgcn_s_barrier();              \
  __builtin_amdgcn_sched_barrier(0);         \
  __builtin_amdgcn_s_setprio(1)

#define PH_E()                               \
  __builtin_amdgcn_s_setprio(0);             \
  __builtin_amdgcn_sched_barrier(0);         \
  __builtin_amdgcn_s_barrier()

// ---------------------------------------------------------------- fp32 [T][DM] -> bf16 [T][xlda] (padded rows)
__global__ void cast_pad_kernel(const float* __restrict__ in,
                                bf16* __restrict__ out, long xlda, int n8) {
  int idx = blockIdx.x * blockDim.x + threadIdx.x;
  int stride = gridDim.x * blockDim.x;
  for (int i = idx; i < n8; i += stride) {
    const int row = i >> 9;              // DM/8 = 512 groups per row
    const int c8 = i & 511;
    const float4 v0 = reinterpret_cast<const float4*>(in)[(long)i * 2];
    const float4 v1 = reinterpret_cast<const float4*>(in)[(long)i * 2 + 1];
    bf16 t[8] = {__float2bfloat16(v0.x), __float2bfloat16(v0.y),
                 __float2bfloat16(v0.z), __float2bfloat16(v0.w),
                 __float2bfloat16(v1.x), __float2bfloat16(v1.y),
                 __float2bfloat16(v1.z), __float2bfloat16(v1.w)};
    *reinterpret_cast<bf16x8*>(&out[(long)row * xlda + (long)c8 * 8]) =
        *reinterpret_cast<bf16x8*>(t);
  }
}

// ---------------------------------------------------------------- fp32 [R][C] -> bf16 [C][out_lda] (transposed, padded rows)
__global__ void transpose_cast_kernel(const float* __restrict__ in,
                                      bf16* __restrict__ out, int R, int C,
                                      long out_lda) {
  __shared__ float tile[32][33];
  const int c0 = blockIdx.x * 32, r0 = blockIdx.y * 32;
  const int tx = threadIdx.x, ty = threadIdx.y;  // block (32,8)
#pragma unroll
  for (int j = 0; j < 4; ++j)
    tile[ty + j * 8][tx] = in[(long)(r0 + ty + j * 8) * C + (c0 + tx)];
  __syncthreads();
#pragma unroll
  for (int j = 0; j < 4; ++j)
    out[(long)(c0 + ty + j * 8) * out_lda + (r0 + tx)] =
        __float2bfloat16(tile[tx][ty + j * 8]);
}

// ---------------------------------------------------------------- GEMM1: gate+up fused (continuous, PHASE-AHEAD reads)
// X:[T][ldx], Gt/Ut:[DFF][ldw]. Grid = 256 = 8 fsub x 32 bm, f-epoch mapping.
// Each phase's operands were ds_read one phase EARLIER; the read-service time
// hides under the MFMA windows. Waits: compiler-counted lgkm + two vmcnt(6)
// (P3 drains (t+1){A0,Bg,Bu}, P4 drains (t+1)A1 — all >=4 phases old).
__global__ __launch_bounds__(512, 2) void gemm_gateup_kernel(
    const bf16* __restrict__ X, const bf16* __restrict__ Gt,
    const bf16* __restrict__ Ut, bf16* __restrict__ H,
    long ldx, long ldw, long ldh) {
  __shared__ __align__(16) bf16 smem[4 * 256 * 64 + 64 * 136];  // 128K + 17K

  const int tid = threadIdx.x;
  const int lane = tid & 63, wid = tid >> 6;
  const int wm = wid >> 2, wn = wid & 3;
  const int fr = lane & 15, fg = lane >> 4;

  const int id = blockIdx.x;
  const int fsub = id & 7, bm = id >> 3;   // grid 256
  const long row0 = (long)bm * 256;

  bf16* const sAb = smem;              // 2 x 16384 elems
  bf16* const sBb = smem + 32768;      // 2 x 16384 elems
  bf16* const sEp = smem + 65536;      // 64 x 136 elems (epilogue quarter)

  // loop-invariant LDS read bases
  const int inner0 = ((fg ^ (fr & 7)) << 4);
  const int inner1 = (((4 | fg) ^ (fr & 7)) << 4);
  const char* aP0 = (const char*)sAb + ((wm * 16 + fr) << 7) + inner0;
  const char* aP1 = (const char*)sAb + ((wm * 16 + fr) << 7) + inner1;
  const char* bP0 = (const char*)sBb + ((wn * 16 + fr) << 7) + inner0;
  const char* bP1 = (const char*)sBb + ((wn * 16 + fr) << 7) + inner1;

  // staging sources; A pointers self-restore every 64 iters; B pointers jump
  // to the next f-block (stride 8 f-blocks = 1024 rows) at each k2 wrap.
  const int r6 = tid >> 3;
  const long sc = (long)((tid & 7) ^ (r6 & 7)) << 3;  // swizzled col (elements)
  const int tu = tid & ~63;
  const bf16* pS0 = X + (row0 + 128 + r6) * ldx + 64 + sc;   // (t+1)A1 hi
  const bf16* pS1 = X + (row0 + 192 + r6) * ldx + 64 + sc;   // (t+1)A1 lo
  const bf16* pS2 = X + (row0 +       r6) * ldx + 128 + sc;  // (t+2)A0 hi
  const bf16* pS3 = X + (row0 +  64 + r6) * ldx + 128 + sc;  // (t+2)A0 lo
  long fcol0 = (long)fsub * 128;                              // s = 0
  const bf16* pS4 = Gt + (fcol0 +      r6) * ldw + 128 + sc;  // (t+2)Bg hi
  const bf16* pS5 = Gt + (fcol0 + 64 + r6) * ldw + 128 + sc;  // (t+2)Bg lo
  const bf16* pS6 = Ut + (fcol0 +      r6) * ldw + 128 + sc;  // (t+2)Bu hi
  const bf16* pS7 = Ut + (fcol0 + 64 + r6) * ldw + 128 + sc;  // (t+2)Bu lo
  const long BJMP = 1024 * ldw - DM;   // f-block jump folded into k-wrap
  long fcolH = fcol0;                  // H column base for epilogue

  f32x4 acc[8][4];  // n=0,1: gate; n=2,3: up (same H cols)
  const f32x4 z = {0.f, 0.f, 0.f, 0.f};
#pragma unroll
  for (int m = 0; m < 8; ++m)
#pragma unroll
    for (int n = 0; n < 4; ++n) acc[m][n] = z;

  // prologue (once): tile0 full (8), tile1 partial (A0 + B, 6)
  stage8k(X, ldx, row0, 0, sAb, 0, tid);
  stage8k(X, ldx, row0, 0, sAb, 512, tid);
  stage8k(X, ldx, row0, 0, sAb, 1024, tid);
  stage8k(X, ldx, row0, 0, sAb, 1536, tid);
  stage8k(Gt, ldw, fcol0, 0, sBb, 0, tid);
  stage8k(Gt, ldw, fcol0, 0, sBb, 512, tid);
  stage8k(Ut, ldw, fcol0 - 128, 0, sBb, 1024, tid);
  stage8k(Ut, ldw, fcol0 - 128, 0, sBb, 1536, tid);
  stage8k(X, ldx, row0, 64, sAb + 16384, 0, tid);
  stage8k(X, ldx, row0, 64, sAb + 16384, 512, tid);
  stage8k(Gt, ldw, fcol0, 64, sBb + 16384, 0, tid);
  stage8k(Gt, ldw, fcol0, 64, sBb + 16384, 512, tid);
  stage8k(Ut, ldw, fcol0 - 128, 64, sBb + 16384, 1024, tid);
  stage8k(Ut, ldw, fcol0 - 128, 64, sBb + 16384, 1536, tid);
  asm volatile("s_waitcnt vmcnt(6)" ::: "memory");
  __builtin_amdgcn_s_barrier();

  bf16x8 a0[4][2], a1[4][2], b0[2][2], b1[2][2];
  // preload tile0's a0 (mh0) and b0 (gate)
#pragma unroll
  for (int m = 0; m < 4; ++m) { a0[m][0] = LDA8(0, 0, m, 0); a0[m][1] = LDA8(0, 0, m, 1); }
#pragma unroll
  for (int n = 0; n < 2; ++n) { b0[n][0] = LDB8(0, n, 0); b0[n][1] = LDB8(0, n, 1); }

  int k1 = 64, k2 = 128;

#pragma unroll 2
  for (int g = 0; g < 896; ++g) {       // 14 fb x 64 K-iters, continuous
    const int par = g & 1;
    const int pb = par << 15;           // compile-time after unroll-2
    const int nb = (par ^ 1) << 15;
    bf16* aCur = sAb + par * 16384;
    bf16* bCur = sBb + par * 16384;
    bf16* aNxt = sAb + (par ^ 1) * 16384;

    // ---- P1: issue b1(t) reads; stage (t+1)A1; MFMA a0 x b0 (gate)
#pragma unroll
    for (int n = 0; n < 2; ++n) { b1[n][0] = LDB8(pb, 2 + n, 0); b1[n][1] = LDB8(pb, 2 + n, 1); }
    gld_lds16(pS0, aNxt + ((1024 + tu) << 3));
    gld_lds16(pS1, aNxt + ((1536 + tu) << 3));
    PH_B();
#pragma unroll
    for (int m = 0; m < 4; ++m)
#pragma unroll
      for (int n = 0; n < 2; ++n)
#pragma unroll
        for (int kk = 0; kk < 2; ++kk)
          acc[m][n] = MFMA(a0[m][kk], b0[n][kk], acc[m][n]);
    PH_E();

    // ---- P2: issue a1(t) reads; stage (t+2)A0; MFMA a0 x b1 (up)
#pragma unroll
    for (int m = 0; m < 4; ++m) { a1[m][0] = LDA8(pb, 1, m, 0); a1[m][1] = LDA8(pb, 1, m, 1); }
    gld_lds16(pS2, aCur + ((0 + tu) << 3));
    gld_lds16(pS3, aCur + ((512 + tu) << 3));
    PH_B();
#pragma unroll
    for (int m = 0; m < 4; ++m)
#pragma unroll
      for (int n = 0; n < 2; ++n)
#pragma unroll
        for (int kk = 0; kk < 2; ++kk)
          acc[m][2 + n] = MFMA(a0[m][kk], b1[n][kk], acc[m][2 + n]);
    PH_E();

    // ---- P3: stage (t+2)Bg; vmcnt(6) [drains (t+1)A0,Bg,Bu]; MFMA a1 x b1;
    //          then issue a0'(t+1) reads from next buffer
    gld_lds16(pS4, bCur + ((0 + tu) << 3));
    gld_lds16(pS5, bCur + ((512 + tu) << 3));
    asm volatile("s_waitcnt vmcnt(6)" ::: "memory");
    PH_B();
#pragma unroll
    for (int m = 0; m < 4; ++m)
#pragma unroll
      for (int n = 0; n < 2; ++n)
#pragma unroll
        for (int kk = 0; kk < 2; ++kk)
          acc[4 + m][2 + n] = MFMA(a1[m][kk], b1[n][kk], acc[4 + m][2 + n]);
    __builtin_amdgcn_s_setprio(0);
    __builtin_amdgcn_sched_barrier(0);
#pragma unroll
    for (int m = 0; m < 4; ++m) { a0[m][0] = LDA8(nb, 0, m, 0); a0[m][1] = LDA8(nb, 0, m, 1); }
    __builtin_amdgcn_sched_barrier(0);
    __builtin_amdgcn_s_barrier();

    // ---- P4: stage (t+2)Bu; vmcnt(6) [drains (t+1)A1]; MFMA a1 x b0;
    //          then issue b0'(t+1) reads from next buffer
    gld_lds16(pS6, bCur + ((1024 + tu) << 3));
    gld_lds16(pS7, bCur + ((1536 + tu) << 3));
    asm volatile("s_waitcnt vmcnt(6)" ::: "memory");
    PH_B();
#pragma unroll
    for (int m = 0; m < 4; ++m)
#pragma unroll
      for (int n = 0; n < 2; ++n)
#pragma unroll
        for (int kk = 0; kk < 2; ++kk)
          acc[4 + m][n] = MFMA(a1[m][kk], b0[n][kk], acc[4 + m][n]);
    __builtin_amdgcn_s_setprio(0);
    __builtin_amdgcn_sched_barrier(0);
#pragma unroll
    for (int n = 0; n < 2; ++n) { b0[n][0] = LDB8(nb, n, 0); b0[n][1] = LDB8(nb, n, 1); }
    __builtin_amdgcn_sched_barrier(0);
    __builtin_amdgcn_s_barrier();

    // ---- advance staging pointers (+64 elem); B jumps f-blocks at k2 wrap
    pS0 += 64; pS1 += 64;
    k1 += 64;
    if (k1 == DM) { k1 = 0; pS0 -= DM; pS1 -= DM; }
    pS2 += 64; pS3 += 64; pS4 += 64; pS5 += 64; pS6 += 64; pS7 += 64;
    k2 += 64;
    if (k2 == DM) {
      k2 = 0; pS2 -= DM; pS3 -= DM;
      pS4 += BJMP; pS5 += BJMP; pS6 += BJMP; pS7 += BJMP;
    }

    // ---- fb boundary: dump+zero acc via quarter-tile NT epilogue (sEp).
    if ((g & 63) == 63) {
#pragma unroll
      for (int q = 0; q < 4; ++q) {
        __builtin_amdgcn_s_barrier();   // prev quarter's reads done
#pragma unroll
        for (int mm = 0; mm < 2; ++mm) {
          const int m = 2 * q + mm;     // compile-time (full unroll)
          const int lr = mm * 32 + wm * 16 + fg * 4;
#pragma unroll
          for (int n = 0; n < 2; ++n) {
            const int lc = n * 64 + wn * 16 + fr;
#pragma unroll
            for (int i = 0; i < 4; ++i) {
              float gv = acc[m][n][i];
              float uv = acc[m][n + 2][i];
              float hv = (gv / (1.0f + __expf(-gv))) * uv;
              sEp[(lr + i) * 136 + lc] = __float2bfloat16(hv);
              acc[m][n][i] = 0.f;
              acc[m][n + 2][i] = 0.f;
            }
          }
        }
        asm volatile("s_waitcnt lgkmcnt(0)" ::: "memory");
        __builtin_amdgcn_s_barrier();
        {
          const int c16 = tid & 15, rb = tid >> 4;
#pragma unroll
          for (int it = 0; it < 2; ++it) {
            const int lr = rb + it * 32;
            i32x4 v = *(const i32x4*)&sEp[lr * 136 + c16 * 8];
            __builtin_nontemporal_store(
                v, (i32x4*)(H + (row0 + q * 64 + lr) * ldh + fcolH + c16 * 8));
          }
        }
      }
      fcolH += 1024;
    }
  }
}

// ---------------------------------------------------------------- GEMM2: out = routing*(H @ Wd)  (phase-ahead reads, bm-major)
__global__ __launch_bounds__(512, 2) void gemm_down_kernel(
    const bf16* __restrict__ A, const bf16* __restrict__ Bt,
    const float* __restrict__ routing, float* __restrict__ out,
    long ldh, long lddt) {
  __shared__ __align__(16) bf16 sA[2][256 * 64];   // 64 KiB
  __shared__ __align__(16) bf16 sB[2][256 * 64];   // 64 KiB

  const int tid = threadIdx.x;
  const int lane = tid & 63, wid = tid >> 6;
  const int wm = wid >> 2, wn = wid & 3;
  const int fr = lane & 15, fg = lane >> 4;

  const int id = blockIdx.x;
  const int xcd = id & 7, j = id >> 3;
  const int bm = j >> 1, bnl = j & 1;
  const long row0 = (long)bm * 256;
  const long col0 = (long)(xcd * 2 + bnl) * 256;
  const int NK = DFF / 64;  // 224

  const int inner0 = ((fg ^ (fr & 7)) << 4);
  const int inner1 = (((4 | fg) ^ (fr & 7)) << 4);
  const char* aP0 = (const char*)&sA[0][0] + ((wm * 16 + fr) << 7) + inner0;
  const char* aP1 = (const char*)&sA[0][0] + ((wm * 16 + fr) << 7) + inner1;
  const char* bP0 = (const char*)&sB[0][0] + ((wn * 16 + fr) << 7) + inner0;
  const char* bP1 = (const char*)&sB[0][0] + ((wn * 16 + fr) << 7) + inner1;

  const int r6 = tid >> 3;
  const long sc = (long)((tid & 7) ^ (r6 & 7)) << 3;
  const int tu = tid & ~63;
  const bf16* pS0 = A  + (row0 + 128 + r6) * ldh  + 64 + sc;   // (t+1)A1 hi
  const bf16* pS1 = A  + (row0 + 192 + r6) * ldh  + 64 + sc;   // (t+1)A1 lo
  const bf16* pS2 = A  + (row0 +       r6) * ldh  + 128 + sc;  // (t+2)A0 hi
  const bf16* pS3 = A  + (row0 +  64 + r6) * ldh  + 128 + sc;  // (t+2)A0 lo
  const bf16* pS4 = Bt + (col0 +       r6) * lddt + 128 + sc;  // (t+2)B0 hi
  const bf16* pS5 = Bt + (col0 +  64 + r6) * lddt + 128 + sc;  // (t+2)B0 lo
  const bf16* pS6 = Bt + (col0 + 128 + r6) * lddt + 128 + sc;  // (t+2)B1 hi
  const bf16* pS7 = Bt + (col0 + 192 + r6) * lddt + 128 + sc;  // (t+2)B1 lo

  f32x4 acc[8][4];
  const f32x4 z = {0.f, 0.f, 0.f, 0.f};
#pragma unroll
  for (int m = 0; m < 8; ++m)
#pragma unroll
    for (int n = 0; n < 4; ++n) acc[m][n] = z;

  // prologue: tile0 full (8), tile1 partial (A0 + B, 6)
  stage8k(A, ldh, row0, 0, (bf16*)sA[0], 0, tid);
  stage8k(A, ldh, row0, 0, (bf16*)sA[0], 512, tid);
  stage8k(A, ldh, row0, 0, (bf16*)sA[0], 1024, tid);
  stage8k(A, ldh, row0, 0, (bf16*)sA[0], 1536, tid);
  stage8k(Bt, lddt, col0, 0, (bf16*)sB[0], 0, tid);
  stage8k(Bt, lddt, col0, 0, (bf16*)sB[0], 512, tid);
  stage8k(Bt, lddt, col0, 0, (bf16*)sB[0], 1024, tid);
  stage8k(Bt, lddt, col0, 0, (bf16*)sB[0], 1536, tid);
  stage8k(A, ldh, row0, 64, (bf16*)sA[1], 0, tid);
  stage8k(A, ldh, row0, 64, (bf16*)sA[1], 512, tid);
  stage8k(Bt, lddt, col0, 64, (bf16*)sB[1], 0, tid);
  stage8k(Bt, lddt, col0, 64, (bf16*)sB[1], 512, tid);
  stage8k(Bt, lddt, col0, 64, (bf16*)sB[1], 1024, tid);
  stage8k(Bt, lddt, col0, 64, (bf16*)sB[1], 1536, tid);
  asm volatile("s_waitcnt vmcnt(6)" ::: "memory");
  __builtin_amdgcn_s_barrier();

  bf16x8 a0[4][2], a1[4][2], b0[2][2], b1[2][2];
#pragma unroll
  for (int m = 0; m < 4; ++m) { a0[m][0] = LDA8(0, 0, m, 0); a0[m][1] = LDA8(0, 0, m, 1); }
#pragma unroll
  for (int n = 0; n < 2; ++n) { b0[n][0] = LDB8(0, n, 0); b0[n][1] = LDB8(0, n, 1); }

  int k1 = 64, k2 = 128;

#pragma unroll 2
  for (int t = 0; t < NK; ++t) {
    const int par = t & 1;
    const int pb = par << 15;
    const int nb = (par ^ 1) << 15;
    bf16* aCur = (bf16*)sA[par];
    bf16* bCur = (bf16*)sB[par];
    bf16* aNxt = (bf16*)sA[par ^ 1];

    // ---- P1: issue b1(t) reads; stage (t+1)A1; MFMA a0 x b0
#pragma unroll
    for (int n = 0; n < 2; ++n) { b1[n][0] = LDB8(pb, 2 + n, 0); b1[n][1] = LDB8(pb, 2 + n, 1); }
    gld_lds16(pS0, aNxt + ((1024 + tu) << 3));
    gld_lds16(pS1, aNxt + ((1536 + tu) << 3));
    PH_B();
#pragma unroll
    for (int m = 0; m < 4; ++m)
#pragma unroll
      for (int n = 0; n < 2; ++n)
#pragma unroll
        for (int kk = 0; kk < 2; ++kk)
          acc[m][n] = MFMA(a0[m][kk], b0[n][kk], acc[m][n]);
    PH_E();

    // ---- P2: issue a1(t) reads; stage (t+2)A0; MFMA a0 x b1
#pragma unroll
    for (int m = 0; m < 4; ++m) { a1[m][0] = LDA8(pb, 1, m, 0); a1[m][1] = LDA8(pb, 1, m, 1); }
    gld_lds16(pS2, aCur + ((0 + tu) << 3));
    gld_lds16(pS3, aCur + ((512 + tu) << 3));
    PH_B();
#pragma unroll
    for (int m = 0; m < 4; ++m)
#pragma unroll
      for (int n = 0; n < 2; ++n)
#pragma unroll
        for (int kk = 0; kk < 2; ++kk)
          acc[m][2 + n] = MFMA(a0[m][kk], b1[n][kk], acc[m][2 + n]);
    PH_E();

    // ---- P3: stage (t+2)B0; vmcnt(6); MFMA a1 x b1; issue a0'(t+1) reads
    gld_lds16(pS4, bCur + ((0 + tu) << 3));
    gld_lds16(pS5, bCur + ((512 + tu) << 3));
    asm volatile("s_waitcnt vmcnt(6)" ::: "memory");
    PH_B();
#pragma unroll
    for (int m = 0; m < 4; ++m)
#pragma unroll
      for (int n = 0; n < 2; ++n)
#pragma unroll
        for (int kk = 0; kk < 2; ++kk)
          acc[4 + m][2 + n] = MFMA(a1[m][kk], b1[n][kk], acc[4 + m][2 + n]);
    __builtin_amdgcn_s_setprio(0);
    __builtin_amdgcn_sched_barrier(0);
#pragma unroll
    for (int m = 0; m < 4; ++m) { a0[m][0] = LDA8(nb, 0, m, 0); a0[m][1] = LDA8(nb, 0, m, 1); }
    __builtin_amdgcn_sched_barrier(0);
    __builtin_amdgcn_s_barrier();

    // ---- P4: stage (t+2)B1; vmcnt(6); MFMA a1 x b0; issue b0'(t+1) reads
    gld_lds16(pS6, bCur + ((1024 + tu) << 3));
    gld_lds16(pS7, bCur + ((1536 + tu) << 3));
    asm volatile("s_waitcnt vmcnt(6)" ::: "memory");
    PH_B();
#pragma unroll
    for (int m = 0; m < 4; ++m)
#pragma unroll
      for (int n = 0; n < 2; ++n)
#pragma unroll
        for (int kk = 0; kk < 2; ++kk)
          acc[4 + m][n] = MFMA(a1[m][kk], b0[n][kk], acc[4 + m][n]);
    __builtin_amdgcn_s_setprio(0);
    __builtin_amdgcn_sched_barrier(0);
#pragma unroll
    for (int n = 0; n < 2; ++n) { b0[n][0] = LDB8(nb, n, 0); b0[n][1] = LDB8(nb, n, 1); }
    __builtin_amdgcn_sched_barrier(0);
    __builtin_amdgcn_s_barrier();

    pS0 += 64; pS1 += 64;
    k1 += 64;
    if (k1 == DFF) { k1 = 0; pS0 -= DFF; pS1 -= DFF; }
    pS2 += 64; pS3 += 64; pS4 += 64; pS5 += 64; pS6 += 64; pS7 += 64;
    k2 += 64;
    if (k2 == DFF) { k2 = 0; pS2 -= DFF; pS3 -= DFF; pS4 -= DFF; pS5 -= DFF; pS6 -= DFF; pS7 -= DFF; }
  }

  // epilogue: out = routing[r] * acc  (plain stores)
#pragma unroll
  for (int m = 0; m < 8; ++m) {
    const long r0w = row0 + m * 32 + wm * 16 + fg * 4;
#pragma unroll
    for (int i = 0; i < 4; ++i) {
      const long r = r0w + i;
      const float rv = routing[r];
#pragma unroll
      for (int n = 0; n < 4; ++n)
        out[r * DM + (col0 + n * 64 + wn * 16 + fr)] = rv * acc[m][n][i];
    }
  }
}

// ---------------------------------------------------------------- launch
extern "C" void kernel_launch(void* const* d_in, const int* in_sizes, int n_in,
                              void* d_out, int out_size, void* d_ws, size_t ws_size,
                              hipStream_t stream) {
  const float* X  = (const float*)d_in[0];
  const float* rw = (const float*)d_in[1];
  const float* Wg = (const float*)d_in[2];
  const float* Wu = (const float*)d_in[3];
  const float* Wd = (const float*)d_in[4];
  float* out = (float*)d_out;

  long XL = DM + 64, WL = DM + 64, DL = DFF + 64, HL = DFF + 64;
  {
    size_t need = 2ull * ((size_t)T_DIM * XL + 2ull * (size_t)DFF * WL +
                          (size_t)DM * DL + (size_t)T_DIM * HL);
    if (ws_size < need) { XL = DM; WL = DM; DL = DFF; HL = DFF; }
  }

  char* ws = (char*)d_ws;
  size_t off = 0;
  bf16* Xb = (bf16*)(ws + off); off += (size_t)T_DIM * XL * 2;
  bf16* GT = (bf16*)(ws + off); off += (size_t)DFF * WL * 2;
  bf16* UT = (bf16*)(ws + off); off += (size_t)DFF * WL * 2;
  bf16* DT = (bf16*)(ws + off); off += (size_t)DM * DL * 2;
  bf16* Hb = (bf16*)(ws + off); off += (size_t)T_DIM * HL * 2;

  cast_pad_kernel<<<2048, 256, 0, stream>>>(X, Xb, XL, T_DIM * DM / 8);
  dim3 tpb(32, 8);
  transpose_cast_kernel<<<dim3(DFF / 32, DM / 32), tpb, 0, stream>>>(Wg, GT, DM, DFF, WL);
  transpose_cast_kernel<<<dim3(DFF / 32, DM / 32), tpb, 0, stream>>>(Wu, UT, DM, DFF, WL);
  transpose_cast_kernel<<<dim3(DM / 32, DFF / 32), tpb, 0, stream>>>(Wd, DT, DFF, DM, DL);

  gemm_gateup_kernel<<<256, 512, 0, stream>>>(Xb, GT, UT, Hb, XL, WL, HL);
  gemm_down_kernel<<<(T_DIM / 256) * (DM / 256), 512, 0, stream>>>(
      Hb, DT, rw, out, HL, DL);
}

// Round 15
// 2585.992 us; speedup vs baseline: 1.0374x; 1.0374x over previous
//
#include <hip/hip_runtime.h>
#include <hip/hip_bf16.h>

using bf16 = __hip_bfloat16;
typedef __attribute__((ext_vector_type(8))) short bf16x8;   // 8 bf16 (4 VGPRs)
typedef __attribute__((ext_vector_type(4))) float f32x4;
typedef __attribute__((ext_vector_type(4))) int i32x4;

#define T_DIM 8192
#define DM    4096
#define DFF   14336

#define MFMA(va, vb, vc) __builtin_amdgcn_mfma_f32_16x16x32_bf16(va, vb, vc, 0, 0, 0)

// ---------------------------------------------------------------- helpers
__device__ __forceinline__ void gld_lds16(const bf16* gsrc, bf16* ldst) {
  auto* g = (const __attribute__((address_space(1))) unsigned int*)gsrc;
  auto* l = (__attribute__((address_space(3))) unsigned int*)ldst;
  __builtin_amdgcn_global_load_lds(g, l, 16, 0, 0);
}

// Prologue-only staging helper (full address math; one-time cost).
__device__ __forceinline__ void stage8k(const bf16* __restrict__ gbase, long lda,
                                        long grow0, long k0, bf16* lds_tile,
                                        int gran0, int tid) {
  const int g = gran0 + tid;            // granule index within tile
  const int row = g >> 3, c16 = g & 7;  // 8 granules (128B) per row
  const bf16* src = gbase + (grow0 + row) * lda + k0 + ((long)(c16 ^ (row & 7)) << 3);
  bf16* dst = lds_tile + ((size_t)(gran0 + (tid & ~63)) << 3);  // wave-uniform base
  gld_lds16(src, dst);
}

// LDS frag reads: per-thread loop-invariant base + compile-time imm offset.
#define LDA8(PB, H, M, KK) (*(const bf16x8*)(aP##KK + (PB) + (H) * 16384 + (M) * 4096))
#define LDB8(PB, N, KK)    (*(const bf16x8*)(bP##KK + (PB) + (N) * 8192))

#define PHASE_MFMA_BEGIN()                            \
  __builtin_amdgcn_s_barrier();                       \
  asm volatile("s_waitcnt lgkmcnt(0)" ::: "memory");  \
  __builtin_amdgcn_sched_barrier(0);                  \
  __builtin_amdgcn_s_setprio(1)

#define PHASE_MFMA_END()                              \
  __builtin_amdgcn_s_setprio(0);                      \
  __builtin_amdgcn_sched_barrier(0);                  \
  __builtin_amdgcn_s_barrier()

// ---------------------------------------------------------------- fp32 [T][DM] -> bf16 [T][xlda] (padded rows)
__global__ void cast_pad_kernel(const float* __restrict__ in,
                                bf16* __restrict__ out, long xlda, int n8) {
  int idx = blockIdx.x * blockDim.x + threadIdx.x;
  int stride = gridDim.x * blockDim.x;
  for (int i = idx; i < n8; i += stride) {
    const int row = i >> 9;              // DM/8 = 512 groups per row
    const int c8 = i & 511;
    const float4 v0 = reinterpret_cast<const float4*>(in)[(long)i * 2];
    const float4 v1 = reinterpret_cast<const float4*>(in)[(long)i * 2 + 1];
    bf16 t[8] = {__float2bfloat16(v0.x), __float2bfloat16(v0.y),
                 __float2bfloat16(v0.z), __float2bfloat16(v0.w),
                 __float2bfloat16(v1.x), __float2bfloat16(v1.y),
                 __float2bfloat16(v1.z), __float2bfloat16(v1.w)};
    *reinterpret_cast<bf16x8*>(&out[(long)row * xlda + (long)c8 * 8]) =
        *reinterpret_cast<bf16x8*>(t);
  }
}

// ---------------------------------------------------------------- fp32 [R][C] -> bf16 [C][out_lda] (64x32 tiles, 128B writes)
// Reads float4-coalesced; writes 128B contiguous bf16 per wave-instruction.
// LDS pad 33: store-read tile[lane][c] -> bank (lane+c)%32, 2-way (free).
__global__ void transpose_cast64_kernel(const float* __restrict__ in,
                                        bf16* __restrict__ out, int R, int C,
                                        long out_lda) {
  __shared__ float tile[64][33];
  const int c0 = blockIdx.x * 32, r0 = blockIdx.y * 64;
  const int tid = threadIdx.x;  // 256
  const int c4 = (tid & 7) * 4, rr = tid >> 3;  // rr 0..31
#pragma unroll
  for (int j = 0; j < 2; ++j) {
    const int r = rr + j * 32;
    const float4 v = *(const float4*)&in[(long)(r0 + r) * C + c0 + c4];
    tile[r][c4] = v.x; tile[r][c4 + 1] = v.y;
    tile[r][c4 + 2] = v.z; tile[r][c4 + 3] = v.w;
  }
  __syncthreads();
  const int lane = tid & 63, w = tid >> 6;  // 4 waves, 8 out-rows each
#pragma unroll
  for (int j = 0; j < 8; ++j) {
    const int c = w * 8 + j;
    out[(long)(c0 + c) * out_lda + r0 + lane] = __float2bfloat16(tile[lane][c]);
  }
}

// ---------------------------------------------------------------- GEMM1: gate+up fused (CONTINUOUS cross-fb pipeline) — r13 verbatim
__global__ __launch_bounds__(512, 2) void gemm_gateup_kernel(
    const bf16* __restrict__ X, const bf16* __restrict__ Gt,
    const bf16* __restrict__ Ut, bf16* __restrict__ H,
    long ldx, long ldw, long ldh) {
  __shared__ __align__(16) bf16 smem[4 * 256 * 64 + 64 * 136];  // 128K + 17K

  const int tid = threadIdx.x;
  const int lane = tid & 63, wid = tid >> 6;
  const int wm = wid >> 2, wn = wid & 3;
  const int fr = lane & 15, fg = lane >> 4;

  const int id = blockIdx.x;
  const int fsub = id & 7, bm = id >> 3;   // grid 256
  const long row0 = (long)bm * 256;

  bf16* const sAb = smem;              // 2 x 16384 elems
  bf16* const sBb = smem + 32768;      // 2 x 16384 elems
  bf16* const sEp = smem + 65536;      // 64 x 136 elems (epilogue quarter)

  const int inner0 = ((fg ^ (fr & 7)) << 4);
  const int inner1 = (((4 | fg) ^ (fr & 7)) << 4);
  const char* aP0 = (const char*)sAb + ((wm * 16 + fr) << 7) + inner0;
  const char* aP1 = (const char*)sAb + ((wm * 16 + fr) << 7) + inner1;
  const char* bP0 = (const char*)sBb + ((wn * 16 + fr) << 7) + inner0;
  const char* bP1 = (const char*)sBb + ((wn * 16 + fr) << 7) + inner1;

  const int r6 = tid >> 3;
  const long sc = (long)((tid & 7) ^ (r6 & 7)) << 3;  // swizzled col (elements)
  const int tu = tid & ~63;
  const bf16* pS0 = X + (row0 + 128 + r6) * ldx + 64 + sc;   // (t+1)A1 hi
  const bf16* pS1 = X + (row0 + 192 + r6) * ldx + 64 + sc;   // (t+1)A1 lo
  const bf16* pS2 = X + (row0 +       r6) * ldx + 128 + sc;  // (t+2)A0 hi
  const bf16* pS3 = X + (row0 +  64 + r6) * ldx + 128 + sc;  // (t+2)A0 lo
  long fcol0 = (long)fsub * 128;                              // s = 0
  const bf16* pS4 = Gt + (fcol0 +      r6) * ldw + 128 + sc;  // (t+2)Bg hi
  const bf16* pS5 = Gt + (fcol0 + 64 + r6) * ldw + 128 + sc;  // (t+2)Bg lo
  const bf16* pS6 = Ut + (fcol0 +      r6) * ldw + 128 + sc;  // (t+2)Bu hi
  const bf16* pS7 = Ut + (fcol0 + 64 + r6) * ldw + 128 + sc;  // (t+2)Bu lo
  const long BJMP = 1024 * ldw - DM;   // f-block jump folded into k-wrap
  long fcolH = fcol0;                  // H column base for epilogue

  f32x4 acc[8][4];  // n=0,1: gate; n=2,3: up (same H cols)
  const f32x4 z = {0.f, 0.f, 0.f, 0.f};
#pragma unroll
  for (int m = 0; m < 8; ++m)
#pragma unroll
    for (int n = 0; n < 4; ++n) acc[m][n] = z;

  // prologue (once): tile0 full (8), tile1 partial (A0 + B, 6)
  stage8k(X, ldx, row0, 0, sAb, 0, tid);
  stage8k(X, ldx, row0, 0, sAb, 512, tid);
  stage8k(X, ldx, row0, 0, sAb, 1024, tid);
  stage8k(X, ldx, row0, 0, sAb, 1536, tid);
  stage8k(Gt, ldw, fcol0, 0, sBb, 0, tid);
  stage8k(Gt, ldw, fcol0, 0, sBb, 512, tid);
  stage8k(Ut, ldw, fcol0 - 128, 0, sBb, 1024, tid);
  stage8k(Ut, ldw, fcol0 - 128, 0, sBb, 1536, tid);
  stage8k(X, ldx, row0, 64, sAb + 16384, 0, tid);
  stage8k(X, ldx, row0, 64, sAb + 16384, 512, tid);
  stage8k(Gt, ldw, fcol0, 64, sBb + 16384, 0, tid);
  stage8k(Gt, ldw, fcol0, 64, sBb + 16384, 512, tid);
  stage8k(Ut, ldw, fcol0 - 128, 64, sBb + 16384, 1024, tid);
  stage8k(Ut, ldw, fcol0 - 128, 64, sBb + 16384, 1536, tid);
  asm volatile("s_waitcnt vmcnt(6)" ::: "memory");
  __builtin_amdgcn_s_barrier();

  bf16x8 a[4][2], b[4][2];
  int k1 = 64, k2 = 128;

#pragma unroll 2
  for (int g = 0; g < 896; ++g) {       // 14 fb x 64 K-iters, continuous
    const int par = g & 1;
    const int pb = par << 15;           // compile-time after unroll-2
    bf16* aCur = sAb + par * 16384;
    bf16* bCur = sBb + par * 16384;
    bf16* aNxt = sAb + (par ^ 1) * 16384;

    // ---- P1: read a-mh0 (8) + b-gate (4); stage (t+1)A1; MFMA mh0 x gate
#pragma unroll
    for (int m = 0; m < 4; ++m) { a[m][0] = LDA8(pb, 0, m, 0); a[m][1] = LDA8(pb, 0, m, 1); }
#pragma unroll
    for (int n = 0; n < 2; ++n) { b[n][0] = LDB8(pb, n, 0); b[n][1] = LDB8(pb, n, 1); }
    gld_lds16(pS0, aNxt + ((1024 + tu) << 3));
    gld_lds16(pS1, aNxt + ((1536 + tu) << 3));
    PHASE_MFMA_BEGIN();
#pragma unroll
    for (int m = 0; m < 4; ++m)
#pragma unroll
      for (int n = 0; n < 2; ++n)
#pragma unroll
        for (int kk = 0; kk < 2; ++kk)
          acc[m][n] = MFMA(a[m][kk], b[n][kk], acc[m][n]);
    PHASE_MFMA_END();

    // ---- P2: read b-up (4); stage (t+2)A0; MFMA mh0 x up
#pragma unroll
    for (int n = 2; n < 4; ++n) { b[n][0] = LDB8(pb, n, 0); b[n][1] = LDB8(pb, n, 1); }
    gld_lds16(pS2, aCur + ((0 + tu) << 3));
    gld_lds16(pS3, aCur + ((512 + tu) << 3));
    PHASE_MFMA_BEGIN();
#pragma unroll
    for (int m = 0; m < 4; ++m)
#pragma unroll
      for (int n = 2; n < 4; ++n)
#pragma unroll
        for (int kk = 0; kk < 2; ++kk)
          acc[m][n] = MFMA(a[m][kk], b[n][kk], acc[m][n]);
    PHASE_MFMA_END();

    // ---- P3: read a-mh1 (8); stage (t+2)B-gate; MFMA mh1 x up
#pragma unroll
    for (int m = 0; m < 4; ++m) { a[m][0] = LDA8(pb, 1, m, 0); a[m][1] = LDA8(pb, 1, m, 1); }
    gld_lds16(pS4, bCur + ((0 + tu) << 3));
    gld_lds16(pS5, bCur + ((512 + tu) << 3));
    PHASE_MFMA_BEGIN();
#pragma unroll
    for (int m = 0; m < 4; ++m)
#pragma unroll
      for (int n = 2; n < 4; ++n)
#pragma unroll
        for (int kk = 0; kk < 2; ++kk)
          acc[4 + m][n] = MFMA(a[m][kk], b[n][kk], acc[4 + m][n]);
    PHASE_MFMA_END();

    // ---- P4: stage (t+2)B-up; vmcnt(6) -> tile t+1 landed; MFMA mh1 x gate
    gld_lds16(pS6, bCur + ((1024 + tu) << 3));
    gld_lds16(pS7, bCur + ((1536 + tu) << 3));
    asm volatile("s_waitcnt vmcnt(6)" ::: "memory");
    PHASE_MFMA_BEGIN();
#pragma unroll
    for (int m = 0; m < 4; ++m)
#pragma unroll
      for (int n = 0; n < 2; ++n)
#pragma unroll
        for (int kk = 0; kk < 2; ++kk)
          acc[4 + m][n] = MFMA(a[m][kk], b[n][kk], acc[4 + m][n]);
    PHASE_MFMA_END();

    // ---- advance staging pointers (+64 elem); B jumps f-blocks at k2 wrap
    pS0 += 64; pS1 += 64;
    k1 += 64;
    if (k1 == DM) { k1 = 0; pS0 -= DM; pS1 -= DM; }
    pS2 += 64; pS3 += 64; pS4 += 64; pS5 += 64; pS6 += 64; pS7 += 64;
    k2 += 64;
    if (k2 == DM) {
      k2 = 0; pS2 -= DM; pS3 -= DM;
      pS4 += BJMP; pS5 += BJMP; pS6 += BJMP; pS7 += BJMP;
    }

    // ---- fb boundary: dump+zero acc via quarter-tile NT epilogue (sEp).
    if ((g & 63) == 63) {
#pragma unroll
      for (int q = 0; q < 4; ++q) {
        __builtin_amdgcn_s_barrier();   // prev quarter's reads done
#pragma unroll
        for (int mm = 0; mm < 2; ++mm) {
          const int m = 2 * q + mm;     // compile-time (full unroll)
          const int lr = mm * 32 + wm * 16 + fg * 4;
#pragma unroll
          for (int n = 0; n < 2; ++n) {
            const int lc = n * 64 + wn * 16 + fr;
#pragma unroll
            for (int i = 0; i < 4; ++i) {
              float gv = acc[m][n][i];
              float uv = acc[m][n + 2][i];
              float hv = (gv / (1.0f + __expf(-gv))) * uv;
              sEp[(lr + i) * 136 + lc] = __float2bfloat16(hv);
              acc[m][n][i] = 0.f;
              acc[m][n + 2][i] = 0.f;
            }
          }
        }
        asm volatile("s_waitcnt lgkmcnt(0)" ::: "memory");
        __builtin_amdgcn_s_barrier();
        {
          const int c16 = tid & 15, rb = tid >> 4;
#pragma unroll
          for (int it = 0; it < 2; ++it) {
            const int lr = rb + it * 32;
            i32x4 v = *(const i32x4*)&sEp[lr * 136 + c16 * 8];
            __builtin_nontemporal_store(
                v, (i32x4*)(H + (row0 + q * 64 + lr) * ldh + fcolH + c16 * 8));
          }
        }
      }
      fcolH += 1024;
    }
  }
}

// ---------------------------------------------------------------- GEMM2: out = routing*(H @ Wd)  (r13 verbatim, bm-major)
__global__ __launch_bounds__(512, 2) void gemm_down_kernel(
    const bf16* __restrict__ A, const bf16* __restrict__ Bt,
    const float* __restrict__ routing, float* __restrict__ out,
    long ldh, long lddt) {
  __shared__ __align__(16) bf16 sA[2][256 * 64];   // 64 KiB
  __shared__ __align__(16) bf16 sB[2][256 * 64];   // 64 KiB

  const int tid = threadIdx.x;
  const int lane = tid & 63, wid = tid >> 6;
  const int wm = wid >> 2, wn = wid & 3;
  const int fr = lane & 15, fg = lane >> 4;

  const int id = blockIdx.x;
  const int xcd = id & 7, j = id >> 3;
  const int bm = j >> 1, bnl = j & 1;
  const long row0 = (long)bm * 256;
  const long col0 = (long)(xcd * 2 + bnl) * 256;
  const int NK = DFF / 64;  // 224

  const int inner0 = ((fg ^ (fr & 7)) << 4);
  const int inner1 = (((4 | fg) ^ (fr & 7)) << 4);
  const char* aP0 = (const char*)&sA[0][0] + ((wm * 16 + fr) << 7) + inner0;
  const char* aP1 = (const char*)&sA[0][0] + ((wm * 16 + fr) << 7) + inner1;
  const char* bP0 = (const char*)&sB[0][0] + ((wn * 16 + fr) << 7) + inner0;
  const char* bP1 = (const char*)&sB[0][0] + ((wn * 16 + fr) << 7) + inner1;

  const int r6 = tid >> 3;
  const long sc = (long)((tid & 7) ^ (r6 & 7)) << 3;
  const int tu = tid & ~63;
  const bf16* pS0 = A  + (row0 + 128 + r6) * ldh  + 64 + sc;   // (t+1)A1 hi
  const bf16* pS1 = A  + (row0 + 192 + r6) * ldh  + 64 + sc;   // (t+1)A1 lo
  const bf16* pS2 = A  + (row0 +       r6) * ldh  + 128 + sc;  // (t+2)A0 hi
  const bf16* pS3 = A  + (row0 +  64 + r6) * ldh  + 128 + sc;  // (t+2)A0 lo
  const bf16* pS4 = Bt + (col0 +       r6) * lddt + 128 + sc;  // (t+2)B0 hi
  const bf16* pS5 = Bt + (col0 +  64 + r6) * lddt + 128 + sc;  // (t+2)B0 lo
  const bf16* pS6 = Bt + (col0 + 128 + r6) * lddt + 128 + sc;  // (t+2)B1 hi
  const bf16* pS7 = Bt + (col0 + 192 + r6) * lddt + 128 + sc;  // (t+2)B1 lo

  f32x4 acc[8][4];
  const f32x4 z = {0.f, 0.f, 0.f, 0.f};
#pragma unroll
  for (int m = 0; m < 8; ++m)
#pragma unroll
    for (int n = 0; n < 4; ++n) acc[m][n] = z;

  // prologue: tile0 full (8), tile1 partial (A0 + B, 6)
  stage8k(A, ldh, row0, 0, (bf16*)sA[0], 0, tid);
  stage8k(A, ldh, row0, 0, (bf16*)sA[0], 512, tid);
  stage8k(A, ldh, row0, 0, (bf16*)sA[0], 1024, tid);
  stage8k(A, ldh, row0, 0, (bf16*)sA[0], 1536, tid);
  stage8k(Bt, lddt, col0, 0, (bf16*)sB[0], 0, tid);
  stage8k(Bt, lddt, col0, 0, (bf16*)sB[0], 512, tid);
  stage8k(Bt, lddt, col0, 0, (bf16*)sB[0], 1024, tid);
  stage8k(Bt, lddt, col0, 0, (bf16*)sB[0], 1536, tid);
  stage8k(A, ldh, row0, 64, (bf16*)sA[1], 0, tid);
  stage8k(A, ldh, row0, 64, (bf16*)sA[1], 512, tid);
  stage8k(Bt, lddt, col0, 64, (bf16*)sB[1], 0, tid);
  stage8k(Bt, lddt, col0, 64, (bf16*)sB[1], 512, tid);
  stage8k(Bt, lddt, col0, 64, (bf16*)sB[1], 1024, tid);
  stage8k(Bt, lddt, col0, 64, (bf16*)sB[1], 1536, tid);
  asm volatile("s_waitcnt vmcnt(6)" ::: "memory");
  __builtin_amdgcn_s_barrier();

  bf16x8 a[4][2], b[4][2];
  int k1 = 64, k2 = 128;

#pragma unroll 2
  for (int t = 0; t < NK; ++t) {
    const int par = t & 1;
    const int pb = par << 15;
    bf16* aCur = (bf16*)sA[par];
    bf16* bCur = (bf16*)sB[par];
    bf16* aNxt = (bf16*)sA[par ^ 1];

    // ---- P1
#pragma unroll
    for (int m = 0; m < 4; ++m) { a[m][0] = LDA8(pb, 0, m, 0); a[m][1] = LDA8(pb, 0, m, 1); }
#pragma unroll
    for (int n = 0; n < 2; ++n) { b[n][0] = LDB8(pb, n, 0); b[n][1] = LDB8(pb, n, 1); }
    gld_lds16(pS0, aNxt + ((1024 + tu) << 3));
    gld_lds16(pS1, aNxt + ((1536 + tu) << 3));
    PHASE_MFMA_BEGIN();
#pragma unroll
    for (int m = 0; m < 4; ++m)
#pragma unroll
      for (int n = 0; n < 2; ++n)
#pragma unroll
        for (int kk = 0; kk < 2; ++kk)
          acc[m][n] = MFMA(a[m][kk], b[n][kk], acc[m][n]);
    PHASE_MFMA_END();

    // ---- P2
#pragma unroll
    for (int n = 2; n < 4; ++n) { b[n][0] = LDB8(pb, n, 0); b[n][1] = LDB8(pb, n, 1); }
    gld_lds16(pS2, aCur + ((0 + tu) << 3));
    gld_lds16(pS3, aCur + ((512 + tu) << 3));
    PHASE_MFMA_BEGIN();
#pragma unroll
    for (int m = 0; m < 4; ++m)
#pragma unroll
      for (int n = 2; n < 4; ++n)
#pragma unroll
        for (int kk = 0; kk < 2; ++kk)
          acc[m][n] = MFMA(a[m][kk], b[n][kk], acc[m][n]);
    PHASE_MFMA_END();

    // ---- P3
#pragma unroll
    for (int m = 0; m < 4; ++m) { a[m][0] = LDA8(pb, 1, m, 0); a[m][1] = LDA8(pb, 1, m, 1); }
    gld_lds16(pS4, bCur + ((0 + tu) << 3));
    gld_lds16(pS5, bCur + ((512 + tu) << 3));
    PHASE_MFMA_BEGIN();
#pragma unroll
    for (int m = 0; m < 4; ++m)
#pragma unroll
      for (int n = 2; n < 4; ++n)
#pragma unroll
        for (int kk = 0; kk < 2; ++kk)
          acc[4 + m][n] = MFMA(a[m][kk], b[n][kk], acc[4 + m][n]);
    PHASE_MFMA_END();

    // ---- P4
    gld_lds16(pS6, bCur + ((1024 + tu) << 3));
    gld_lds16(pS7, bCur + ((1536 + tu) << 3));
    asm volatile("s_waitcnt vmcnt(6)" ::: "memory");
    PHASE_MFMA_BEGIN();
#pragma unroll
    for (int m = 0; m < 4; ++m)
#pragma unroll
      for (int n = 0; n < 2; ++n)
#pragma unroll
        for (int kk = 0; kk < 2; ++kk)
          acc[4 + m][n] = MFMA(a[m][kk], b[n][kk], acc[4 + m][n]);
    PHASE_MFMA_END();

    pS0 += 64; pS1 += 64;
    k1 += 64;
    if (k1 == DFF) { k1 = 0; pS0 -= DFF; pS1 -= DFF; }
    pS2 += 64; pS3 += 64; pS4 += 64; pS5 += 64; pS6 += 64; pS7 += 64;
    k2 += 64;
    if (k2 == DFF) { k2 = 0; pS2 -= DFF; pS3 -= DFF; pS4 -= DFF; pS5 -= DFF; pS6 -= DFF; pS7 -= DFF; }
  }

  // epilogue: out = routing[r] * acc  (plain stores)
#pragma unroll
  for (int m = 0; m < 8; ++m) {
    const long r0w = row0 + m * 32 + wm * 16 + fg * 4;
#pragma unroll
    for (int i = 0; i < 4; ++i) {
      const long r = r0w + i;
      const float rv = routing[r];
#pragma unroll
      for (int n = 0; n < 4; ++n)
        out[r * DM + (col0 + n * 64 + wn * 16 + fr)] = rv * acc[m][n][i];
    }
  }
}

// ---------------------------------------------------------------- launch
extern "C" void kernel_launch(void* const* d_in, const int* in_sizes, int n_in,
                              void* d_out, int out_size, void* d_ws, size_t ws_size,
                              hipStream_t stream) {
  const float* X  = (const float*)d_in[0];
  const float* rw = (const float*)d_in[1];
  const float* Wg = (const float*)d_in[2];
  const float* Wu = (const float*)d_in[3];
  const float* Wd = (const float*)d_in[4];
  float* out = (float*)d_out;

  long XL = DM + 64, WL = DM + 64, DL = DFF + 64, HL = DFF + 64;
  {
    size_t need = 2ull * ((size_t)T_DIM * XL + 2ull * (size_t)DFF * WL +
                          (size_t)DM * DL + (size_t)T_DIM * HL);
    if (ws_size < need) { XL = DM; WL = DM; DL = DFF; HL = DFF; }
  }

  char* ws = (char*)d_ws;
  size_t off = 0;
  bf16* Xb = (bf16*)(ws + off); off += (size_t)T_DIM * XL * 2;
  bf16* GT = (bf16*)(ws + off); off += (size_t)DFF * WL * 2;
  bf16* UT = (bf16*)(ws + off); off += (size_t)DFF * WL * 2;
  bf16* DT = (bf16*)(ws + off); off += (size_t)DM * DL * 2;
  bf16* Hb = (bf16*)(ws + off); off += (size_t)T_DIM * HL * 2;

  cast_pad_kernel<<<2048, 256, 0, stream>>>(X, Xb, XL, T_DIM * DM / 8);
  // Wg/Wu: [DM][DFF] -> [DFF][WL]; tiles 64 rows x 32 cols
  transpose_cast64_kernel<<<dim3(DFF / 32, DM / 64), 256, 0, stream>>>(Wg, GT, DM, DFF, WL);
  transpose_cast64_kernel<<<dim3(DFF / 32, DM / 64), 256, 0, stream>>>(Wu, UT, DM, DFF, WL);
  // Wd: [DFF][DM] -> [DM][DL]
  transpose_cast64_kernel<<<dim3(DM / 32, DFF / 64), 256, 0, stream>>>(Wd, DT, DFF, DM, DL);

  gemm_gateup_kernel<<<256, 512, 0, stream>>>(Xb, GT, UT, Hb, XL, WL, HL);
  gemm_down_kernel<<<(T_DIM / 256) * (DM / 256), 512, 0, stream>>>(
      Hb, DT, rw, out, HL, DL);
}